// Round 10
// baseline (580.941 us; speedup 1.0000x reference)
//
#include <hip/hip_runtime.h>

#define NN 8192
#define FF 256

typedef _Float16 h8 __attribute__((ext_vector_type(8)));
typedef _Float16 h4 __attribute__((ext_vector_type(4)));
typedef float    f4 __attribute__((ext_vector_type(4)));
typedef int      i4v __attribute__((ext_vector_type(4)));

__device__ __forceinline__ unsigned fenc(float x) {
  unsigned u = __float_as_uint(x);
  return (u & 0x80000000u) ? ~u : (u | 0x80000000u);
}
__device__ __forceinline__ float fdec(unsigned e) {
  unsigned u = (e & 0x80000000u) ? (e ^ 0x80000000u) : ~e;
  return __uint_as_float(u);
}

// ---------------- Kernel 1: Wh = h@W (fp32 vector), s1, s2(f16), wfrag -------
// grid 512 x 256 thr. Block = 16 rows of h = half of k-tile (blockIdx>>1).
// wfrag[(kt*16+n)*512 + lane*8 + j] = Wh[kt*32 + (lane>>4)*8 + j][n*16 + (lane&15)]
__global__ __launch_bounds__(256) void k_wh(
    const float* __restrict__ h, const float* __restrict__ W,
    const float* __restrict__ a, _Float16* __restrict__ wfrag,
    float* __restrict__ s1, _Float16* __restrict__ s2h,
    unsigned* __restrict__ s2maxe) {
  __shared__ float hs[16 * 256];
  __shared__ _Float16 whs[16 * 264];
  const int t = threadIdx.x;
  const int r0 = blockIdx.x * 16;
#pragma unroll
  for (int i = 0; i < 4; ++i) {
    int idx = i * 1024 + t * 4;
    *(f4*)&hs[idx] = *(const f4*)&h[(size_t)r0 * 256 + idx];
  }
  __syncthreads();
  const int lane = t & 63;
  const int wv = t >> 6;
  const int rg = wv * 4;
  const int c4 = lane * 4;
  float acc[4][4];
#pragma unroll
  for (int i = 0; i < 4; ++i)
#pragma unroll
    for (int k = 0; k < 4; ++k) acc[i][k] = 0.f;
  f4 w[8];
#pragma unroll
  for (int i = 0; i < 8; ++i) w[i] = *(const f4*)&W[i * 256 + c4];
  for (int f = 0; f < 256; f += 8) {
    f4 nw[8];
    if (f < 248) {
#pragma unroll
      for (int i = 0; i < 8; ++i) nw[i] = *(const f4*)&W[(f + 8 + i) * 256 + c4];
    }
#pragma unroll
    for (int i = 0; i < 4; ++i) {
      f4 h0 = *(const f4*)&hs[(rg + i) * 256 + f];
      f4 h1 = *(const f4*)&hs[(rg + i) * 256 + f + 4];
#pragma unroll
      for (int k = 0; k < 4; ++k)
        acc[i][k] += h0[0]*w[0][k] + h0[1]*w[1][k] + h0[2]*w[2][k] + h0[3]*w[3][k]
                   + h1[0]*w[4][k] + h1[1]*w[5][k] + h1[2]*w[6][k] + h1[3]*w[7][k];
    }
    if (f < 248) {
#pragma unroll
      for (int i = 0; i < 8; ++i) w[i] = nw[i];
    }
  }
  float a1v[4], a2v[4];
#pragma unroll
  for (int k = 0; k < 4; ++k) { a1v[k] = a[c4 + k]; a2v[k] = a[256 + c4 + k]; }
#pragma unroll
  for (int i = 0; i < 4; ++i) {
    h4 hh;
    float p1 = 0.f, p2 = 0.f;
#pragma unroll
    for (int k = 0; k < 4; ++k) {
      hh[k] = (_Float16)acc[i][k];
      p1 += acc[i][k] * a1v[k];
      p2 += acc[i][k] * a2v[k];
    }
    *(h4*)&whs[(rg + i) * 264 + c4] = hh;
#pragma unroll
    for (int off = 32; off; off >>= 1) {
      p1 += __shfl_xor(p1, off);
      p2 += __shfl_xor(p2, off);
    }
    if (lane == 0) {
      const int r = r0 + rg + i;
      s1[r] = p1;
      s2h[r] = (_Float16)p2;
      atomicMax(s2maxe, fenc(p2));
    }
  }
  __syncthreads();
  {
    const int kt = blockIdx.x >> 1;
    const int hb = blockIdx.x & 1;
    const int lp = hb * 32 + (t & 31);
    const int kb = ((t & 31) >> 4) * 8;
    const int m16e = t & 15;
#pragma unroll
    for (int p = 0; p < 2; ++p) {
      const int n = (t >> 5) + p * 8;
      h8 v;
#pragma unroll
      for (int j = 0; j < 8; ++j) v[j] = whs[(kb + j) * 264 + n * 16 + m16e];
      *(h8*)&wfrag[(((size_t)kt * 16 + n) << 9) + lp * 8] = v;
    }
  }
}

// ---------------- Kernel 2: fused attention — barrier-free dataflow ----------
// grid 512 = (rt 0..127)*4 + kq; 256 thr (4 waves); 2 blocks/CU.
// Wave w owns rows r0 + w*16 + m16 for its kq k-quarter x ALL 256 cols.
// P is computed DIRECTLY in A-fragment layout (lane(m16,q) holds
// A[m16][q*8+j]) -> no LDS P, no barriers, no convoying. B-frags loaded
// per-wave from global; all blocks on an XCD share kq (kq = blockIdx&3,
// XCD = blockIdx%8) -> the 1 MB kq wfrag slice is L2-resident.
// Per iter: [B(kt) x16] [adj(kt+2) x2, nontemporal] [scores(kt)] [16 MFMA].
// MFMA's B-wait = vmcnt(2): adj stays in flight; adj age ~2 iters >> HBM lat.
__global__ __launch_bounds__(256, 2) void k_gat(
    const int* __restrict__ adj, const _Float16* __restrict__ wfrag,
    const float* __restrict__ s1g, const _Float16* __restrict__ s2h,
    const unsigned* __restrict__ s2maxe,
    float* __restrict__ o0, float* __restrict__ o1,
    float* __restrict__ o2, float* __restrict__ o3,
    float* __restrict__ lbuf) {
  __shared__ _Float16 s2l[2048];   // 4 KB: this kq-quarter's s2
  const int t = threadIdx.x;
  const int lane = t & 63;
  const int w = t >> 6;          // 0..3
  const int q = lane >> 4;       // 0..3
  const int m16 = lane & 15;
  const int rt = (int)blockIdx.x >> 2;
  const int kq = (int)blockIdx.x & 3;
  const int r0 = rt * 64;

  ((h8*)s2l)[t] = ((const h8*)(s2h + kq * 2048))[t];

  const int srow = w * 16 + m16;             // lane's row (local)
  const float s2m = fdec(*s2maxe);
  const float s1r = s1g[r0 + srow];
  const float u0 = s1r + s2m;
  const float mi = fmaxf(u0, 0.2f * u0);     // >= leaky(s1r+s2[j]) for all j
  const float s1mi = s1r - mi;

  f4 acc[16];
#pragma unroll
  for (int n = 0; n < 16; ++n)
#pragma unroll
    for (int e = 0; e < 4; ++e) acc[n][e] = 0.f;
  float lsum = 0.f;

  const int* adjp = adj + (size_t)(r0 + srow) * NN + kq * 2048 + q * 8;
  __syncthreads();   // s2l ready (only barrier in the kernel)

  // adj pipeline depth 2 (consumed at age ~2 iters)
  i4v c0 = __builtin_nontemporal_load((const i4v*)(adjp));
  i4v c1 = __builtin_nontemporal_load((const i4v*)(adjp + 4));
  i4v d0 = __builtin_nontemporal_load((const i4v*)(adjp + 32));
  i4v d1 = __builtin_nontemporal_load((const i4v*)(adjp + 36));

#pragma unroll 1
  for (int kt = 0; kt < 64; ++kt) {
    // (1) B(kt): 16 fully-coalesced loads from the L2-resident kq slice
    const _Float16* wfb =
        wfrag + (((size_t)(kq * 64 + kt) * 16) << 9) + lane * 8;
    h8 bb[16];
#pragma unroll
    for (int n = 0; n < 16; ++n) bb[n] = *(const h8*)(wfb + (n << 9));
    // (2) adj(kt+2): HBM, nontemporal, consumed two iters later
    i4v e0 = d0, e1 = d1;
    if (kt < 62) {
      e0 = __builtin_nontemporal_load((const i4v*)(adjp + (kt + 2) * 32));
      e1 = __builtin_nontemporal_load((const i4v*)(adjp + (kt + 2) * 32 + 4));
    }
    // (3) scores(kt): p = exp(leaky(s1+s2)-mi), directly in A-frag layout
    const h8 s2c = *(const h8*)&s2l[kt * 32 + q * 8];
    h8 pa;
#pragma unroll
    for (int j = 0; j < 4; ++j) {
      const float s2v = (float)s2c[j];
      const float u = s1r + s2v;
      const float arg = s1mi + s2v - 0.8f * fminf(u, 0.f);
      const float pv = (c0[j] > 0) ? __expf(arg) : 0.f;
      lsum += pv;
      pa[j] = (_Float16)pv;
    }
#pragma unroll
    for (int j = 0; j < 4; ++j) {
      const float s2v = (float)s2c[4 + j];
      const float u = s1r + s2v;
      const float arg = s1mi + s2v - 0.8f * fminf(u, 0.f);
      const float pv = (c1[j] > 0) ? __expf(arg) : 0.f;
      lsum += pv;
      pa[4 + j] = (_Float16)pv;
    }
    // (4) MFMA: 16 n-tiles; B-wait = vmcnt(2), adj prefetch stays in flight
#pragma unroll
    for (int n = 0; n < 16; ++n)
      acc[n] = __builtin_amdgcn_mfma_f32_16x16x32_f16(pa, bb[n], acc[n], 0, 0, 0);
    // (5) rotate adj pipeline
    c0 = d0; c1 = d1; d0 = e0; d1 = e1;
  }

  // partial denominator for row srow: combine the 4 q-lanes
  lsum += __shfl_xor(lsum, 16);
  lsum += __shfl_xor(lsum, 32);
  if (q == 0) lbuf[kq * NN + r0 + srow] = lsum;

  // partial O: plain stores (C layout: row=q*4+v, col=n*16+m16)
  float* ob = (kq == 0) ? o0 : (kq == 1) ? o1 : (kq == 2) ? o2 : o3;
#pragma unroll
  for (int n = 0; n < 16; ++n)
#pragma unroll
    for (int v = 0; v < 4; ++v)
      ob[(size_t)(r0 + w * 16 + q * 4 + v) * FF + n * 16 + m16] = acc[n][v];
}

// ---------------- Kernel 3: combine quarters, normalize, elu -----------------
__global__ __launch_bounds__(256) void k_fin(
    float* __restrict__ out, const float* __restrict__ o1,
    const float* __restrict__ o2, const float* __restrict__ o3,
    const float* __restrict__ lbuf) {
  const int t = threadIdx.x;
  const int row = blockIdx.x * 16 + (t >> 4);
  const int c0 = (t & 15) * 16;
  const float linv = 1.0f / (lbuf[row] + lbuf[NN + row] +
                             lbuf[2 * NN + row] + lbuf[3 * NN + row]);
#pragma unroll
  for (int i = 0; i < 4; ++i) {
    const size_t off = (size_t)row * FF + c0 + i * 4;
    f4 v0 = *(const f4*)&out[off];
    f4 v1 = *(const f4*)&o1[off];
    f4 v2 = *(const f4*)&o2[off];
    f4 v3 = *(const f4*)&o3[off];
    f4 o;
#pragma unroll
    for (int e = 0; e < 4; ++e) {
      float x = (v0[e] + v1[e] + v2[e] + v3[e]) * linv;
      o[e] = (x > 0.f) ? x : (__expf(x) - 1.f);
    }
    *(f4*)&out[off] = o;
  }
}

extern "C" void kernel_launch(void* const* d_in, const int* in_sizes, int n_in,
                              void* d_out, int out_size, void* d_ws, size_t ws_size,
                              hipStream_t stream) {
  const float* h   = (const float*)d_in[0];
  const int*   adj = (const int*)d_in[1];
  const float* W   = (const float*)d_in[2];
  const float* a   = (const float*)d_in[3];
  float* out = (float*)d_out;

  char* ws = (char*)d_ws;
  _Float16* wfrag = (_Float16*)ws;                                // 4 MB
  float*    o1    = (float*)(ws + (4u << 20));                    // 8 MB
  float*    o2    = (float*)(ws + (12u << 20));                   // 8 MB
  float*    o3    = (float*)(ws + (20u << 20));                   // 8 MB
  float*    lbuf  = (float*)(ws + (28u << 20));                   // 128 KB
  unsigned* s2me  = (unsigned*)(ws + (28u << 20) + 131072);       // 4 B (+60 pad)
  float*    s1    = (float*)(ws + (28u << 20) + 131136);          // 32 KB
  _Float16* s2h   = (_Float16*)(ws + (28u << 20) + 131136 + 32768); // 16 KB

  hipMemsetAsync(s2me, 0, 4, stream);   // fenc-domain -inf
  k_wh<<<512, 256, 0, stream>>>(h, W, a, wfrag, s1, s2h, s2me);
  k_gat<<<512, 256, 0, stream>>>(adj, wfrag, s1, s2h, s2me,
                                 out, o1, o2, o3, lbuf);
  k_fin<<<512, 256, 0, stream>>>(out, o1, o2, o3, lbuf);
}

// Round 11
// 564.944 us; speedup vs baseline: 1.0283x; 1.0283x over previous
//
#include <hip/hip_runtime.h>

#define NN 8192
#define FF 256

typedef _Float16 h8 __attribute__((ext_vector_type(8)));
typedef _Float16 h4 __attribute__((ext_vector_type(4)));
typedef float    f4 __attribute__((ext_vector_type(4)));
typedef int      i4v __attribute__((ext_vector_type(4)));

__device__ __forceinline__ unsigned fenc(float x) {
  unsigned u = __float_as_uint(x);
  return (u & 0x80000000u) ? ~u : (u | 0x80000000u);
}
__device__ __forceinline__ float fdec(unsigned e) {
  unsigned u = (e & 0x80000000u) ? (e ^ 0x80000000u) : ~e;
  return __uint_as_float(u);
}

// ---------------- Kernel 1: Wh = h@W (fp32 vector), s1, s2(f16), wfrag -------
// grid 512 x 256 thr. Block = 16 rows of h = half of k-tile (blockIdx>>1).
// wfrag[(kt*16+n)*512 + lane*8 + j] = Wh[kt*32 + (lane>>4)*8 + j][n*16 + (lane&15)]
__global__ __launch_bounds__(256) void k_wh(
    const float* __restrict__ h, const float* __restrict__ W,
    const float* __restrict__ a, _Float16* __restrict__ wfrag,
    float* __restrict__ s1, _Float16* __restrict__ s2h,
    unsigned* __restrict__ s2maxe) {
  __shared__ float hs[16 * 256];
  __shared__ _Float16 whs[16 * 264];
  const int t = threadIdx.x;
  const int r0 = blockIdx.x * 16;
#pragma unroll
  for (int i = 0; i < 4; ++i) {
    int idx = i * 1024 + t * 4;
    *(f4*)&hs[idx] = *(const f4*)&h[(size_t)r0 * 256 + idx];
  }
  __syncthreads();
  const int lane = t & 63;
  const int wv = t >> 6;
  const int rg = wv * 4;
  const int c4 = lane * 4;
  float acc[4][4];
#pragma unroll
  for (int i = 0; i < 4; ++i)
#pragma unroll
    for (int k = 0; k < 4; ++k) acc[i][k] = 0.f;
  f4 w[8];
#pragma unroll
  for (int i = 0; i < 8; ++i) w[i] = *(const f4*)&W[i * 256 + c4];
  for (int f = 0; f < 256; f += 8) {
    f4 nw[8];
    if (f < 248) {
#pragma unroll
      for (int i = 0; i < 8; ++i) nw[i] = *(const f4*)&W[(f + 8 + i) * 256 + c4];
    }
#pragma unroll
    for (int i = 0; i < 4; ++i) {
      f4 h0 = *(const f4*)&hs[(rg + i) * 256 + f];
      f4 h1 = *(const f4*)&hs[(rg + i) * 256 + f + 4];
#pragma unroll
      for (int k = 0; k < 4; ++k)
        acc[i][k] += h0[0]*w[0][k] + h0[1]*w[1][k] + h0[2]*w[2][k] + h0[3]*w[3][k]
                   + h1[0]*w[4][k] + h1[1]*w[5][k] + h1[2]*w[6][k] + h1[3]*w[7][k];
    }
    if (f < 248) {
#pragma unroll
      for (int i = 0; i < 8; ++i) w[i] = nw[i];
    }
  }
  float a1v[4], a2v[4];
#pragma unroll
  for (int k = 0; k < 4; ++k) { a1v[k] = a[c4 + k]; a2v[k] = a[256 + c4 + k]; }
#pragma unroll
  for (int i = 0; i < 4; ++i) {
    h4 hh;
    float p1 = 0.f, p2 = 0.f;
#pragma unroll
    for (int k = 0; k < 4; ++k) {
      hh[k] = (_Float16)acc[i][k];
      p1 += acc[i][k] * a1v[k];
      p2 += acc[i][k] * a2v[k];
    }
    *(h4*)&whs[(rg + i) * 264 + c4] = hh;
#pragma unroll
    for (int off = 32; off; off >>= 1) {
      p1 += __shfl_xor(p1, off);
      p2 += __shfl_xor(p2, off);
    }
    if (lane == 0) {
      const int r = r0 + rg + i;
      s1[r] = p1;
      s2h[r] = (_Float16)p2;
      atomicMax(s2maxe, fenc(p2));
    }
  }
  __syncthreads();
  {
    const int kt = blockIdx.x >> 1;
    const int hb = blockIdx.x & 1;
    const int lp = hb * 32 + (t & 31);
    const int kb = ((t & 31) >> 4) * 8;
    const int m16e = t & 15;
#pragma unroll
    for (int p = 0; p < 2; ++p) {
      const int n = (t >> 5) + p * 8;
      h8 v;
#pragma unroll
      for (int j = 0; j < 8; ++j) v[j] = whs[(kb + j) * 264 + n * 16 + m16e];
      *(h8*)&wfrag[(((size_t)kt * 16 + n) << 9) + lp * 8] = v;
    }
  }
}

// ---------------- Kernel 2: fused attention — barrier-free dataflow v2 -------
// grid 512 = rt(128) x kq(4); 256 thr = 4 waves = (rg 0..1) x (ch 0..1).
// Wave (rg,ch): rows r0+rg*32+{m16,16+m16} (2 row-tiles) x cols ch*128+[0,128)
// (8 n-tiles) x its kq k-quarter. P stays in A-frag registers (no LDS P, no
// sync-barriers). Each B h8 feeds 2 MFMAs (2 row-tiles) -> half the B bytes
// per MFMA vs r10. Intra-block sharing (B: rg-pairs, adj: ch-pairs) is served
// by L1; a BARE s_barrier (no waitcnt -> no vmem drain) keeps waves aligned.
// All blocks on an XCD share kq (kq=blockIdx&3, XCD=blockIdx%8) -> 1 MB wfrag
// slice is L2-resident.
__global__ __launch_bounds__(256, 2) void k_gat(
    const int* __restrict__ adj, const _Float16* __restrict__ wfrag,
    const float* __restrict__ s1g, const _Float16* __restrict__ s2h,
    const unsigned* __restrict__ s2maxe,
    float* __restrict__ o0, float* __restrict__ o1,
    float* __restrict__ o2, float* __restrict__ o3,
    float* __restrict__ lbuf) {
  __shared__ _Float16 s2l[2048];   // 4 KB: this kq-quarter's s2
  const int t = threadIdx.x;
  const int lane = t & 63;
  const int w = t >> 6;          // 0..3
  const int rg = w >> 1;         // row-group
  const int ch = w & 1;          // col-half
  const int q = lane >> 4;       // 0..3
  const int m16 = lane & 15;
  const int rt = (int)blockIdx.x >> 2;
  const int kq = (int)blockIdx.x & 3;
  const int r0 = rt * 64;

  ((h8*)s2l)[t] = ((const h8*)(s2h + kq * 2048))[t];

  const float s2m = fdec(*s2maxe);
  float s1r[2], s1mi[2];
#pragma unroll
  for (int R = 0; R < 2; ++R) {
    s1r[R] = s1g[r0 + rg * 32 + R * 16 + m16];
    const float u0 = s1r[R] + s2m;
    const float mi = fmaxf(u0, 0.2f * u0);   // >= leaky(s1r+s2[j]) for all j
    s1mi[R] = s1r[R] - mi;
  }

  f4 acc[2][8];
#pragma unroll
  for (int R = 0; R < 2; ++R)
#pragma unroll
    for (int n = 0; n < 8; ++n)
#pragma unroll
      for (int e = 0; e < 4; ++e) acc[R][n][e] = 0.f;
  float lsum[2] = {0.f, 0.f};

  const int* adjr0 = adj + (size_t)(r0 + rg * 32 + m16) * NN + kq * 2048 + q * 8;
  const int* adjr1 = adjr0 + 16 * NN;
  __syncthreads();   // s2l ready (only full barrier in the kernel)

  // adj pipeline depth 1 (consumed next iter; issued after B each iter)
  i4v c00 = __builtin_nontemporal_load((const i4v*)(adjr0));
  i4v c01 = __builtin_nontemporal_load((const i4v*)(adjr0 + 4));
  i4v c10 = __builtin_nontemporal_load((const i4v*)(adjr1));
  i4v c11 = __builtin_nontemporal_load((const i4v*)(adjr1 + 4));

#pragma unroll 1
  for (int kt = 0; kt < 64; ++kt) {
    // (0) bare barrier: align waves so L1 catches the 2x intra-block sharing
    __builtin_amdgcn_s_barrier();
    // (1) B(kt): 8 coalesced loads from the L2-resident kq slice
    const _Float16* wfb =
        wfrag + (((size_t)((kq * 64 + kt) * 16 + ch * 8)) << 9) + lane * 8;
    h8 bb[8];
#pragma unroll
    for (int n = 0; n < 8; ++n) bb[n] = *(const h8*)(wfb + (n << 9));
    // (2) adj(kt+1): HBM/LLC, nontemporal, consumed next iter
    i4v n00 = c00, n01 = c01, n10 = c10, n11 = c11;
    if (kt < 63) {
      n00 = __builtin_nontemporal_load((const i4v*)(adjr0 + (kt + 1) * 32));
      n01 = __builtin_nontemporal_load((const i4v*)(adjr0 + (kt + 1) * 32 + 4));
      n10 = __builtin_nontemporal_load((const i4v*)(adjr1 + (kt + 1) * 32));
      n11 = __builtin_nontemporal_load((const i4v*)(adjr1 + (kt + 1) * 32 + 4));
    }
    // (3) scores(kt): 16 cells/lane, directly in A-frag layout
    const h8 s2c = *(const h8*)&s2l[kt * 32 + q * 8];
    h8 pa0, pa1;
#pragma unroll
    for (int j = 0; j < 8; ++j) {
      const float s2v = (float)s2c[j];
      const int mk0 = (j < 4) ? c00[j] : c01[j - 4];
      const int mk1 = (j < 4) ? c10[j] : c11[j - 4];
      const float u0 = s1r[0] + s2v;
      const float u1 = s1r[1] + s2v;
      const float g0 = s1mi[0] + s2v - 0.8f * fminf(u0, 0.f);
      const float g1 = s1mi[1] + s2v - 0.8f * fminf(u1, 0.f);
      const float p0 = (mk0 > 0) ? __expf(g0) : 0.f;
      const float p1 = (mk1 > 0) ? __expf(g1) : 0.f;
      lsum[0] += p0; lsum[1] += p1;
      pa0[j] = (_Float16)p0; pa1[j] = (_Float16)p1;
    }
    // (4) MFMA: 2 row-tiles x 8 n-tiles; B-wait = vmcnt(4), adj in flight
#pragma unroll
    for (int n = 0; n < 8; ++n) {
      acc[0][n] = __builtin_amdgcn_mfma_f32_16x16x32_f16(pa0, bb[n], acc[0][n], 0, 0, 0);
      acc[1][n] = __builtin_amdgcn_mfma_f32_16x16x32_f16(pa1, bb[n], acc[1][n], 0, 0, 0);
    }
    // (5) rotate adj pipeline
    c00 = n00; c01 = n01; c10 = n10; c11 = n11;
  }

  // partial denominators: combine the 4 q-lanes of each row
#pragma unroll
  for (int R = 0; R < 2; ++R) {
    float v = lsum[R];
    v += __shfl_xor(v, 16);
    v += __shfl_xor(v, 32);
    if (q == 0) lbuf[kq * NN + r0 + rg * 32 + R * 16 + m16] = v;
  }

  // partial O: plain stores (C layout: row=q*4+v, col=n*16+m16)
  float* ob = (kq == 0) ? o0 : (kq == 1) ? o1 : (kq == 2) ? o2 : o3;
#pragma unroll
  for (int R = 0; R < 2; ++R)
#pragma unroll
    for (int n = 0; n < 8; ++n)
#pragma unroll
      for (int v = 0; v < 4; ++v)
        ob[(size_t)(r0 + rg * 32 + R * 16 + q * 4 + v) * FF +
           ch * 128 + n * 16 + m16] = acc[R][n][v];
}

// ---------------- Kernel 3: combine quarters, normalize, elu -----------------
__global__ __launch_bounds__(256) void k_fin(
    float* __restrict__ out, const float* __restrict__ o1,
    const float* __restrict__ o2, const float* __restrict__ o3,
    const float* __restrict__ lbuf) {
  const int t = threadIdx.x;
  const int row = blockIdx.x * 16 + (t >> 4);
  const int c0 = (t & 15) * 16;
  const float linv = 1.0f / (lbuf[row] + lbuf[NN + row] +
                             lbuf[2 * NN + row] + lbuf[3 * NN + row]);
#pragma unroll
  for (int i = 0; i < 4; ++i) {
    const size_t off = (size_t)row * FF + c0 + i * 4;
    f4 v0 = *(const f4*)&out[off];
    f4 v1 = *(const f4*)&o1[off];
    f4 v2 = *(const f4*)&o2[off];
    f4 v3 = *(const f4*)&o3[off];
    f4 o;
#pragma unroll
    for (int e = 0; e < 4; ++e) {
      float x = (v0[e] + v1[e] + v2[e] + v3[e]) * linv;
      o[e] = (x > 0.f) ? x : (__expf(x) - 1.f);
    }
    *(f4*)&out[off] = o;
  }
}

extern "C" void kernel_launch(void* const* d_in, const int* in_sizes, int n_in,
                              void* d_out, int out_size, void* d_ws, size_t ws_size,
                              hipStream_t stream) {
  const float* h   = (const float*)d_in[0];
  const int*   adj = (const int*)d_in[1];
  const float* W   = (const float*)d_in[2];
  const float* a   = (const float*)d_in[3];
  float* out = (float*)d_out;

  char* ws = (char*)d_ws;
  _Float16* wfrag = (_Float16*)ws;                                // 4 MB
  float*    o1    = (float*)(ws + (4u << 20));                    // 8 MB
  float*    o2    = (float*)(ws + (12u << 20));                   // 8 MB
  float*    o3    = (float*)(ws + (20u << 20));                   // 8 MB
  float*    lbuf  = (float*)(ws + (28u << 20));                   // 128 KB
  unsigned* s2me  = (unsigned*)(ws + (28u << 20) + 131072);       // 4 B (+60 pad)
  float*    s1    = (float*)(ws + (28u << 20) + 131136);          // 32 KB
  _Float16* s2h   = (_Float16*)(ws + (28u << 20) + 131136 + 32768); // 16 KB

  hipMemsetAsync(s2me, 0, 4, stream);   // fenc-domain -inf
  k_wh<<<512, 256, 0, stream>>>(h, W, a, wfrag, s1, s2h, s2me);
  k_gat<<<512, 256, 0, stream>>>(adj, wfrag, s1, s2h, s2me,
                                 out, o1, o2, o3, lbuf);
  k_fin<<<512, 256, 0, stream>>>(out, o1, o2, o3, lbuf);
}

// Round 12
// 529.642 us; speedup vs baseline: 1.0969x; 1.0667x over previous
//
#include <hip/hip_runtime.h>

#define NN 8192
#define FF 256

typedef _Float16 h8 __attribute__((ext_vector_type(8)));
typedef _Float16 h4 __attribute__((ext_vector_type(4)));
typedef float    f4 __attribute__((ext_vector_type(4)));
typedef int      i4v __attribute__((ext_vector_type(4)));

typedef __attribute__((address_space(1))) const unsigned int guint;
typedef __attribute__((address_space(3))) unsigned int luint;

// async 16B/lane global->LDS DMA (m97 pattern): lds dest = uniform base + lane*16
__device__ __forceinline__ void gl_lds16(const _Float16* g, _Float16* l) {
  __builtin_amdgcn_global_load_lds((guint*)g, (luint*)l, 16, 0, 0);
}

__device__ __forceinline__ unsigned fenc(float x) {
  unsigned u = __float_as_uint(x);
  return (u & 0x80000000u) ? ~u : (u | 0x80000000u);
}
__device__ __forceinline__ float fdec(unsigned e) {
  unsigned u = (e & 0x80000000u) ? (e ^ 0x80000000u) : ~e;
  return __uint_as_float(u);
}

// ---------------- Kernel 1: Wh = h@W (fp32 vector), s1, s2(f16), wfrag -------
// grid 512 x 256 thr. Block = 16 rows of h = half of k-tile (blockIdx>>1).
// wfrag[(kt*16+n)*512 + lane*8 + j] = Wh[kt*32 + (lane>>4)*8 + j][n*16 + (lane&15)]
__global__ __launch_bounds__(256) void k_wh(
    const float* __restrict__ h, const float* __restrict__ W,
    const float* __restrict__ a, _Float16* __restrict__ wfrag,
    float* __restrict__ s1, _Float16* __restrict__ s2h,
    unsigned* __restrict__ s2maxe) {
  __shared__ float hs[16 * 256];
  __shared__ _Float16 whs[16 * 264];
  const int t = threadIdx.x;
  const int r0 = blockIdx.x * 16;
#pragma unroll
  for (int i = 0; i < 4; ++i) {
    int idx = i * 1024 + t * 4;
    *(f4*)&hs[idx] = *(const f4*)&h[(size_t)r0 * 256 + idx];
  }
  __syncthreads();
  const int lane = t & 63;
  const int wv = t >> 6;
  const int rg = wv * 4;
  const int c4 = lane * 4;
  float acc[4][4];
#pragma unroll
  for (int i = 0; i < 4; ++i)
#pragma unroll
    for (int k = 0; k < 4; ++k) acc[i][k] = 0.f;
  f4 w[8];
#pragma unroll
  for (int i = 0; i < 8; ++i) w[i] = *(const f4*)&W[i * 256 + c4];
  for (int f = 0; f < 256; f += 8) {
    f4 nw[8];
    if (f < 248) {
#pragma unroll
      for (int i = 0; i < 8; ++i) nw[i] = *(const f4*)&W[(f + 8 + i) * 256 + c4];
    }
#pragma unroll
    for (int i = 0; i < 4; ++i) {
      f4 h0 = *(const f4*)&hs[(rg + i) * 256 + f];
      f4 h1 = *(const f4*)&hs[(rg + i) * 256 + f + 4];
#pragma unroll
      for (int k = 0; k < 4; ++k)
        acc[i][k] += h0[0]*w[0][k] + h0[1]*w[1][k] + h0[2]*w[2][k] + h0[3]*w[3][k]
                   + h1[0]*w[4][k] + h1[1]*w[5][k] + h1[2]*w[6][k] + h1[3]*w[7][k];
    }
    if (f < 248) {
#pragma unroll
      for (int i = 0; i < 8; ++i) w[i] = nw[i];
    }
  }
  float a1v[4], a2v[4];
#pragma unroll
  for (int k = 0; k < 4; ++k) { a1v[k] = a[c4 + k]; a2v[k] = a[256 + c4 + k]; }
#pragma unroll
  for (int i = 0; i < 4; ++i) {
    h4 hh;
    float p1 = 0.f, p2 = 0.f;
#pragma unroll
    for (int k = 0; k < 4; ++k) {
      hh[k] = (_Float16)acc[i][k];
      p1 += acc[i][k] * a1v[k];
      p2 += acc[i][k] * a2v[k];
    }
    *(h4*)&whs[(rg + i) * 264 + c4] = hh;
#pragma unroll
    for (int off = 32; off; off >>= 1) {
      p1 += __shfl_xor(p1, off);
      p2 += __shfl_xor(p2, off);
    }
    if (lane == 0) {
      const int r = r0 + rg + i;
      s1[r] = p1;
      s2h[r] = (_Float16)p2;
      atomicMax(s2maxe, fenc(p2));
    }
  }
  __syncthreads();
  {
    const int kt = blockIdx.x >> 1;
    const int hb = blockIdx.x & 1;
    const int lp = hb * 32 + (t & 31);
    const int kb = ((t & 31) >> 4) * 8;
    const int m16e = t & 15;
#pragma unroll
    for (int p = 0; p < 2; ++p) {
      const int n = (t >> 5) + p * 8;
      h8 v;
#pragma unroll
      for (int j = 0; j < 8; ++j) v[j] = whs[(kb + j) * 264 + n * 16 + m16e];
      *(h8*)&wfrag[(((size_t)kt * 16 + n) << 9) + lp * 8] = v;
    }
  }
}

// ---------------- Kernel 2: fused attention — LDS-staged B -------------------
// grid 512 = rt(128) x kq(4); 256 thr (4 waves); 2 blocks/CU.
// Wave w owns rows r0+w*16+m16 (16 rows) x ALL 256 cols x the kq k-quarter.
// P lives in A-frag registers (scores computed by the row-owning wave).
// B (16 KB per 32-k tile) is DMA-staged ONCE per block via global_load_lds
// (each L2 line fetched once/block, not once/wave: 4x L1-line cut vs r10),
// then ds_read broadcast at 128 B/cyc. One raw s_barrier + full waitcnt per
// iter; at the wait point all outstanding vmem (stage(kt), adj(kt+1)) is a
// full iteration old -> ~zero drain. kq = blockIdx&3 is XCD-uniform -> the
// 1 MB wfrag slice is L2-resident.
__global__ __launch_bounds__(256, 2) void k_gat(
    const int* __restrict__ adj, const _Float16* __restrict__ wfrag,
    const float* __restrict__ s1g, const _Float16* __restrict__ s2h,
    const unsigned* __restrict__ s2maxe,
    float* __restrict__ o0, float* __restrict__ o1,
    float* __restrict__ o2, float* __restrict__ o3,
    float* __restrict__ lbuf) {
  __shared__ _Float16 Bl[2][8192];   // 32 KB: B tile double-buffer
  __shared__ _Float16 s2l[2048];     // 4 KB: this kq-quarter's s2
  const int t = threadIdx.x;
  const int lane = t & 63;
  const int w = t >> 6;          // 0..3
  const int q = lane >> 4;       // 0..3
  const int m16 = lane & 15;
  const int rt = (int)blockIdx.x >> 2;
  const int kq = (int)blockIdx.x & 3;
  const int r0 = rt * 64;

  ((h8*)s2l)[t] = ((const h8*)(s2h + kq * 2048))[t];

  const int srow = w * 16 + m16;             // lane's row (local)
  const float s2m = fdec(*s2maxe);
  const float s1r = s1g[r0 + srow];
  const float u0 = s1r + s2m;
  const float mi = fmaxf(u0, 0.2f * u0);     // >= leaky(s1r+s2[j]) for all j
  const float s1mi = s1r - mi;

  f4 acc[16];
#pragma unroll
  for (int n = 0; n < 16; ++n)
#pragma unroll
    for (int e = 0; e < 4; ++e) acc[n][e] = 0.f;
  float lsum = 0.f;

  const int* adjp = adj + (size_t)(r0 + srow) * NN + kq * 2048 + q * 8;
  const _Float16* wsrc = wfrag + ((size_t)(kq * 64) << 13);   // this quarter's tiles

  // prologue: stage B(0), adj(0) and adj(1) into regs
  {
    const _Float16* s0 = wsrc;   // tile 0, contiguous 16 KB
#pragma unroll
    for (int i = 0; i < 4; ++i)
      gl_lds16(s0 + w * 2048 + i * 512 + lane * 8, &Bl[0][w * 2048 + i * 512]);
  }
  i4v c0 = __builtin_nontemporal_load((const i4v*)(adjp));
  i4v c1 = __builtin_nontemporal_load((const i4v*)(adjp + 4));
  i4v d0 = __builtin_nontemporal_load((const i4v*)(adjp + 32));
  i4v d1 = __builtin_nontemporal_load((const i4v*)(adjp + 36));

#pragma unroll 1
  for (int kt = 0; kt < 64; ++kt) {
    // (0) full wait + barrier: outstanding vmem (stage(kt), adj(kt+1)) is a
    //     full iteration old -> near-zero drain; publishes Bl[kt&1] + s2l
    __builtin_amdgcn_s_waitcnt(0x0070);   // vmcnt(0) lgkmcnt(0), exp ignored
    __builtin_amdgcn_s_barrier();
    // (1) stage B(kt+1) (DMA, consumed next iter after next barrier)
    if (kt < 63) {
      const _Float16* sn = wsrc + ((size_t)(kt + 1) << 13);
#pragma unroll
      for (int i = 0; i < 4; ++i)
        gl_lds16(sn + w * 2048 + i * 512 + lane * 8,
                 &Bl[(kt + 1) & 1][w * 2048 + i * 512]);
    }
    // (2) adj(kt+2): nontemporal HBM, consumed in 2 iters
    i4v e0 = d0, e1 = d1;
    if (kt < 62) {
      e0 = __builtin_nontemporal_load((const i4v*)(adjp + (kt + 2) * 32));
      e1 = __builtin_nontemporal_load((const i4v*)(adjp + (kt + 2) * 32 + 4));
    }
    // (3) scores(kt) from adj regs + s2l, directly in A-frag layout
    const h8 s2c = *(const h8*)&s2l[kt * 32 + q * 8];
    h8 pa;
#pragma unroll
    for (int j = 0; j < 8; ++j) {
      const float s2v = (float)s2c[j];
      const float u = s1r + s2v;
      const float arg = s1mi + s2v - 0.8f * fminf(u, 0.f);
      const int msk = (j < 4) ? c0[j] : c1[j - 4];
      const float pv = (msk > 0) ? __expf(arg) : 0.f;
      lsum += pv;
      pa[j] = (_Float16)pv;
    }
    // (4) ds_read B(kt) + MFMA, 4 n-tiles at a time (bounded liveness)
    const _Float16* bufc = &Bl[kt & 1][0];
#pragma unroll
    for (int n4 = 0; n4 < 4; ++n4) {
      h8 b0 = *(const h8*)&bufc[(n4 * 4 + 0) * 512 + lane * 8];
      h8 b1 = *(const h8*)&bufc[(n4 * 4 + 1) * 512 + lane * 8];
      h8 b2 = *(const h8*)&bufc[(n4 * 4 + 2) * 512 + lane * 8];
      h8 b3 = *(const h8*)&bufc[(n4 * 4 + 3) * 512 + lane * 8];
      acc[n4 * 4 + 0] = __builtin_amdgcn_mfma_f32_16x16x32_f16(pa, b0, acc[n4 * 4 + 0], 0, 0, 0);
      acc[n4 * 4 + 1] = __builtin_amdgcn_mfma_f32_16x16x32_f16(pa, b1, acc[n4 * 4 + 1], 0, 0, 0);
      acc[n4 * 4 + 2] = __builtin_amdgcn_mfma_f32_16x16x32_f16(pa, b2, acc[n4 * 4 + 2], 0, 0, 0);
      acc[n4 * 4 + 3] = __builtin_amdgcn_mfma_f32_16x16x32_f16(pa, b3, acc[n4 * 4 + 3], 0, 0, 0);
    }
    // (5) rotate adj pipeline
    c0 = d0; c1 = d1; d0 = e0; d1 = e1;
  }

  // partial denominator for row srow: combine the 4 q-lanes
  lsum += __shfl_xor(lsum, 16);
  lsum += __shfl_xor(lsum, 32);
  if (q == 0) lbuf[kq * NN + r0 + srow] = lsum;

  // partial O: plain stores (C layout: row=q*4+v, col=n*16+m16)
  float* ob = (kq == 0) ? o0 : (kq == 1) ? o1 : (kq == 2) ? o2 : o3;
#pragma unroll
  for (int n = 0; n < 16; ++n)
#pragma unroll
    for (int v = 0; v < 4; ++v)
      ob[(size_t)(r0 + w * 16 + q * 4 + v) * FF + n * 16 + m16] = acc[n][v];
}

// ---------------- Kernel 3: combine quarters, normalize, elu -----------------
__global__ __launch_bounds__(256) void k_fin(
    float* __restrict__ out, const float* __restrict__ o1,
    const float* __restrict__ o2, const float* __restrict__ o3,
    const float* __restrict__ lbuf) {
  const int t = threadIdx.x;
  const int row = blockIdx.x * 16 + (t >> 4);
  const int c0 = (t & 15) * 16;
  const float linv = 1.0f / (lbuf[row] + lbuf[NN + row] +
                             lbuf[2 * NN + row] + lbuf[3 * NN + row]);
#pragma unroll
  for (int i = 0; i < 4; ++i) {
    const size_t off = (size_t)row * FF + c0 + i * 4;
    f4 v0 = *(const f4*)&out[off];
    f4 v1 = *(const f4*)&o1[off];
    f4 v2 = *(const f4*)&o2[off];
    f4 v3 = *(const f4*)&o3[off];
    f4 o;
#pragma unroll
    for (int e = 0; e < 4; ++e) {
      float x = (v0[e] + v1[e] + v2[e] + v3[e]) * linv;
      o[e] = (x > 0.f) ? x : (__expf(x) - 1.f);
    }
    *(f4*)&out[off] = o;
  }
}

extern "C" void kernel_launch(void* const* d_in, const int* in_sizes, int n_in,
                              void* d_out, int out_size, void* d_ws, size_t ws_size,
                              hipStream_t stream) {
  const float* h   = (const float*)d_in[0];
  const int*   adj = (const int*)d_in[1];
  const float* W   = (const float*)d_in[2];
  const float* a   = (const float*)d_in[3];
  float* out = (float*)d_out;

  char* ws = (char*)d_ws;
  _Float16* wfrag = (_Float16*)ws;                                // 4 MB
  float*    o1    = (float*)(ws + (4u << 20));                    // 8 MB
  float*    o2    = (float*)(ws + (12u << 20));                   // 8 MB
  float*    o3    = (float*)(ws + (20u << 20));                   // 8 MB
  float*    lbuf  = (float*)(ws + (28u << 20));                   // 128 KB
  unsigned* s2me  = (unsigned*)(ws + (28u << 20) + 131072);       // 4 B (+60 pad)
  float*    s1    = (float*)(ws + (28u << 20) + 131136);          // 32 KB
  _Float16* s2h   = (_Float16*)(ws + (28u << 20) + 131136 + 32768); // 16 KB

  hipMemsetAsync(s2me, 0, 4, stream);   // fenc-domain -inf
  k_wh<<<512, 256, 0, stream>>>(h, W, a, wfrag, s1, s2h, s2me);
  k_gat<<<512, 256, 0, stream>>>(adj, wfrag, s1, s2h, s2me,
                                 out, o1, o2, o3, lbuf);
  k_fin<<<512, 256, 0, stream>>>(out, o1, o2, o3, lbuf);
}